// Round 1
// baseline (726.041 us; speedup 1.0000x reference)
//
#include <hip/hip_runtime.h>

// VectorQuantizer: x[16384][64] fp32, codebook[8192][64] fp32
// out = concat(discrete one-hot [16384][8192] fp32, quantized [16384][64] fp32)
// argmin_k ||x - c_k||^2  ==  argmax_k (x . c_k - 0.5*||c_k||^2)

#define NROWS 16384
#define KCODES 8192
#define DDIM 64

// ---------------- kernel 0: cn2[k] = 0.5*||c_k||^2 ----------------
__global__ __launch_bounds__(256) void k_cn2(const float* __restrict__ cb,
                                             float* __restrict__ cn2) {
    int i = blockIdx.x * 256 + threadIdx.x;   // 0..8191
    const float4* c4 = (const float4*)(cb + (size_t)i * DDIM);
    float s = 0.f;
#pragma unroll
    for (int j = 0; j < 16; ++j) {
        float4 v = c4[j];
        s = fmaf(v.x, v.x, s); s = fmaf(v.y, v.y, s);
        s = fmaf(v.z, v.z, s); s = fmaf(v.w, v.w, s);
    }
    cn2[i] = 0.5f * s;
}

// ---------------- kernel 1: main GEMM + argmax + zero-fill ----------------
// grid = 512: blockIdx = rb*2 + half. Block: 64 rows x 4096 codes (one half).
// Tiles of 128 codes. Per-thread: 8 rows x 4 codes fp32 accumulators.
// LDS: x transposed [64][72], codebook tile transposed [64][132]
//   (strides keep float4 reads 16B-aligned and compute reads conflict-free).
__global__ __launch_bounds__(256, 2) void k_main(const float* __restrict__ x,
                                                 const float* __restrict__ cb,
                                                 const float* __restrict__ cn2,
                                                 float* __restrict__ discrete,
                                                 float* __restrict__ cand_val,
                                                 int* __restrict__ cand_idx) {
    __shared__ float x_lds[DDIM][72];
    __shared__ float c_lds[DDIM][132];

    const int t = threadIdx.x;
    const int rb = blockIdx.x >> 1;
    const int half = blockIdx.x & 1;
    const int row0 = rb * 64;
    const int code0 = half * 4096;
    const int rg = t & 7;    // row group: rows rg*8 .. rg*8+7
    const int cg = t >> 3;   // code group: codes cg*4 .. cg*4+3 (within tile)

    // stage x tile transposed: 64 rows x 64 dims
#pragma unroll
    for (int i = 0; i < 4; ++i) {
        int l = i * 256 + t;
        int r = l >> 4, dc = l & 15;
        float4 v = *(const float4*)(x + (size_t)(row0 + r) * DDIM + dc * 4);
        x_lds[dc * 4 + 0][r] = v.x;
        x_lds[dc * 4 + 1][r] = v.y;
        x_lds[dc * 4 + 2][r] = v.z;
        x_lds[dc * 4 + 3][r] = v.w;
    }

    float best_val[8];
    int   best_idx[8];
#pragma unroll
    for (int j = 0; j < 8; ++j) { best_val[j] = -3.4e38f; best_idx[j] = 0; }

    for (int ct = 0; ct < 32; ++ct) {
        const int ctile0 = code0 + ct * 128;
        __syncthreads();  // previous tile's reads done before restaging
        // stage codebook tile transposed: 128 codes x 64 dims
#pragma unroll
        for (int i = 0; i < 8; ++i) {
            int l = i * 256 + t;
            int code = l >> 4, dc = l & 15;
            float4 v = *(const float4*)(cb + (size_t)(ctile0 + code) * DDIM + dc * 4);
            c_lds[dc * 4 + 0][code] = v.x;
            c_lds[dc * 4 + 1][code] = v.y;
            c_lds[dc * 4 + 2][code] = v.z;
            c_lds[dc * 4 + 3][code] = v.w;
        }
        __syncthreads();

        // init acc with -0.5*||c||^2  (score = x.c - 0.5||c||^2, maximize)
        float4 cnv = *(const float4*)(cn2 + ctile0 + cg * 4);
        float acc[8][4];
#pragma unroll
        for (int j = 0; j < 8; ++j) {
            acc[j][0] = -cnv.x; acc[j][1] = -cnv.y;
            acc[j][2] = -cnv.z; acc[j][3] = -cnv.w;
        }

#pragma unroll 8
        for (int d = 0; d < DDIM; ++d) {
            float4 xa = *(const float4*)&x_lds[d][rg * 8];
            float4 xb = *(const float4*)&x_lds[d][rg * 8 + 4];
            float4 cv = *(const float4*)&c_lds[d][cg * 4];
            float xr[8] = {xa.x, xa.y, xa.z, xa.w, xb.x, xb.y, xb.z, xb.w};
            float cr[4] = {cv.x, cv.y, cv.z, cv.w};
#pragma unroll
            for (int j = 0; j < 8; ++j)
#pragma unroll
                for (int m = 0; m < 4; ++m)
                    acc[j][m] = fmaf(xr[j], cr[m], acc[j][m]);
        }

        // fold tile into running best (ascending code order + strict > => first-min ties)
#pragma unroll
        for (int j = 0; j < 8; ++j) {
#pragma unroll
            for (int m = 0; m < 4; ++m) {
                int code = ctile0 + cg * 4 + m;
                if (acc[j][m] > best_val[j]) { best_val[j] = acc[j][m]; best_idx[j] = code; }
            }
        }

        // interleaved zero-fill of discrete for this tile's 64 rows x 128 cols
        {
            float4 z = make_float4(0.f, 0.f, 0.f, 0.f);
#pragma unroll
            for (int i = 0; i < 8; ++i) {
                int e = i * 256 + t;
                int r = e >> 5, c4i = e & 31;
                float4* dst = (float4*)(discrete + (size_t)(row0 + r) * KCODES + ctile0) + c4i;
                *dst = z;
            }
        }
    }

    // cross-thread reduce per row (reuse LDS; safe after barrier)
    __syncthreads();
    float* red_val = &c_lds[0][0];      // [64][33]
    int*   red_idx = (int*)&x_lds[0][0];// [64][33]
#pragma unroll
    for (int j = 0; j < 8; ++j) {
        red_val[(rg * 8 + j) * 33 + cg] = best_val[j];
        red_idx[(rg * 8 + j) * 33 + cg] = best_idx[j];
    }
    __syncthreads();
    if (t < 64) {
        float bv = red_val[t * 33 + 0];
        int   bi = red_idx[t * 33 + 0];
        for (int c = 1; c < 32; ++c) {
            float v = red_val[t * 33 + c];
            int  id = red_idx[t * 33 + c];
            if (v > bv || (v == bv && id < bi)) { bv = v; bi = id; }
        }
        cand_val[(size_t)(row0 + t) * 2 + half] = bv;
        cand_idx[(size_t)(row0 + t) * 2 + half] = bi;
    }
}

// ---------------- kernel 2: combine halves, write 1.0 + quantized ----------------
__global__ __launch_bounds__(256) void k_finish(const float* __restrict__ cb,
                                                const float* __restrict__ cand_val,
                                                const int* __restrict__ cand_idx,
                                                float* __restrict__ discrete,
                                                float* __restrict__ quantized) {
    __shared__ int sidx[256];
    const int t = threadIdx.x;
    const int row0 = blockIdx.x * 256;
    const int row = row0 + t;
    float v0 = cand_val[(size_t)row * 2 + 0];
    float v1 = cand_val[(size_t)row * 2 + 1];
    int   i0 = cand_idx[(size_t)row * 2 + 0];
    int   i1 = cand_idx[(size_t)row * 2 + 1];
    int bi = (v1 > v0) ? i1 : i0;   // tie -> half 0 (lower idx), matches argmin-first
    sidx[t] = bi;
    discrete[(size_t)row * KCODES + bi] = 1.0f;
    __syncthreads();
    // quantized rows: 256 rows x 16 float4
#pragma unroll
    for (int i = 0; i < 16; ++i) {
        int e = i * 256 + t;
        int r = e >> 4, c = e & 15;
        float4 v = *((const float4*)(cb + (size_t)sidx[r] * DDIM) + c);
        *((float4*)(quantized + (size_t)(row0 + r) * DDIM) + c) = v;
    }
}

extern "C" void kernel_launch(void* const* d_in, const int* in_sizes, int n_in,
                              void* d_out, int out_size, void* d_ws, size_t ws_size,
                              hipStream_t stream) {
    const float* x  = (const float*)d_in[0];   // 16*32*32*64
    const float* cb = (const float*)d_in[1];   // 8192*64

    float* discrete  = (float*)d_out;                          // 16384*8192
    float* quantized = (float*)d_out + (size_t)NROWS * KCODES; // 16384*64

    float* cn2      = (float*)d_ws;            // 8192 floats
    float* cand_val = cn2 + KCODES;            // 16384*2 floats
    int*   cand_idx = (int*)(cand_val + NROWS * 2);

    k_cn2<<<KCODES / 256, 256, 0, stream>>>(cb, cn2);
    k_main<<<512, 256, 0, stream>>>(x, cb, cn2, discrete, cand_val, cand_idx);
    k_finish<<<NROWS / 256, 256, 0, stream>>>(cb, cand_val, cand_idx, discrete, quantized);
}

// Round 3
// 667.412 us; speedup vs baseline: 1.0878x; 1.0878x over previous
//
#include <hip/hip_runtime.h>

// VectorQuantizer: x[16384][64] fp32, codebook[8192][64] fp32
// out = concat(discrete one-hot [16384][8192] fp32, quantized [16384][64] fp32)
// argmin_k ||x - c_k||^2  ==  argmax_k (x . c_k - 0.5*||c_k||^2)

#define NROWS 16384
#define KCODES 8192
#define DDIM 64
#define RPB 128     // rows per block
#define CPT 128     // codes per tile
#define NQ 4        // code quarters
#define QCODES (KCODES / NQ)   // 2048
#define NTILES (QCODES / CPT)  // 16

typedef float f32x4 __attribute__((ext_vector_type(4)));  // clang vector for nontemporal builtin

// ---------------- kernel 0: cn2[k] = 0.5*||c_k||^2 ----------------
__global__ __launch_bounds__(256) void k_cn2(const float* __restrict__ cb,
                                             float* __restrict__ cn2) {
    int i = blockIdx.x * 256 + threadIdx.x;
    const float4* c4 = (const float4*)(cb + (size_t)i * DDIM);
    float s = 0.f;
#pragma unroll
    for (int j = 0; j < 16; ++j) {
        float4 v = c4[j];
        s = fmaf(v.x, v.x, s); s = fmaf(v.y, v.y, s);
        s = fmaf(v.z, v.z, s); s = fmaf(v.w, v.w, s);
    }
    cn2[i] = 0.5f * s;
}

// ---------------- kernel 1: main GEMM + argmax + zero-fill ----------------
// grid = 512: blockIdx = rb*4 + quarter. Block: 128 rows x 2048 codes.
// Tiles of 128 codes. Per-thread: 8 rows x 8 codes fp32 accumulators.
// LDS layouts (transposed, swizzled so staging writes AND compute reads are
// conflict-free):
//   x_lds[d][colx(r)]  stride 136; colx: granule g=r>>2, gphys=g^((g>>3)&3)
//     -> compute-read cols are per-thread constants; read 2-way (free);
//        staging write 16-way but only once per kernel (negligible).
//   c_lds[d][colc(code,d)] stride 132; colc: granule g=code>>2,
//     gphys=(g+(d>>2))&31 -> staging write banks 2-way (free);
//     compute reads broadcast/conflict-free.
__global__ __launch_bounds__(256, 2) void k_main(const float* __restrict__ x,
                                                 const float* __restrict__ cb,
                                                 const float* __restrict__ cn2,
                                                 float* __restrict__ discrete,
                                                 float* __restrict__ cand_val,
                                                 int* __restrict__ cand_idx) {
    __shared__ float x_lds[DDIM][136];
    __shared__ float c_lds[DDIM][132];

    const int t = threadIdx.x;
    const int rb = blockIdx.x >> 2;
    const int q  = blockIdx.x & 3;
    const int row0 = rb * RPB;
    const int code0 = q * QCODES;
    const int rg = t & 15;   // row group: rows rg*8 .. rg*8+7
    const int cg = t >> 4;   // code group: codes cg*8 .. cg*8+7 (within tile)

    // ---- stage x tile transposed+swizzled: 128 rows x 64 dims ----
#pragma unroll
    for (int i = 0; i < 8; ++i) {
        int l = i * 256 + t;
        int r = l >> 4, dc = l & 15;
        float4 v = *(const float4*)(x + (size_t)(row0 + r) * DDIM + dc * 4);
        int gr = r >> 2;
        int gphys = gr ^ ((gr >> 3) & 3);
        int col = gphys * 4 + (r & 3);
        x_lds[dc * 4 + 0][col] = v.x;
        x_lds[dc * 4 + 1][col] = v.y;
        x_lds[dc * 4 + 2][col] = v.z;
        x_lds[dc * 4 + 3][col] = v.w;
    }

    // per-thread constant x read columns (granules 2rg, 2rg+1)
    const int g0 = 2 * rg, g1 = 2 * rg + 1;
    const int xc0 = (g0 ^ ((g0 >> 3) & 3)) * 4;
    const int xc1 = (g1 ^ ((g1 >> 3) & 3)) * 4;

    float best_val[8];
    int   best_idx[8];
#pragma unroll
    for (int j = 0; j < 8; ++j) { best_val[j] = -3.4e38f; best_idx[j] = 0; }

    const f32x4 zero4 = {0.f, 0.f, 0.f, 0.f};

    for (int ct = 0; ct < NTILES; ++ct) {
        const int ctile0 = code0 + ct * CPT;
        __syncthreads();  // previous tile's LDS reads done; prior stores drained
        // ---- stage codebook tile transposed+rotated: 128 codes x 64 dims ----
#pragma unroll
        for (int i = 0; i < 8; ++i) {
            int l = i * 256 + t;
            int code = l >> 4, dcc = l & 15;
            float4 v = *(const float4*)(cb + (size_t)(ctile0 + code) * DDIM + dcc * 4);
            int gr = code >> 2;
            int gphys = (gr + dcc) & 31;
            int col = gphys * 4 + (code & 3);
            c_lds[dcc * 4 + 0][col] = v.x;
            c_lds[dcc * 4 + 1][col] = v.y;
            c_lds[dcc * 4 + 2][col] = v.z;
            c_lds[dcc * 4 + 3][col] = v.w;
        }
        __syncthreads();

        // ---- zero-fill discrete for this tile (drains under the FMA loop) ----
#pragma unroll
        for (int i = 0; i < 16; ++i) {
            int e = i * 256 + t;
            int r = e >> 5, c4i = e & 31;
            f32x4* dst = (f32x4*)(discrete + (size_t)(row0 + r) * KCODES + ctile0) + c4i;
            __builtin_nontemporal_store(zero4, dst);
        }

        // ---- init acc with -0.5*||c||^2 ----
        float4 cna = *(const float4*)(cn2 + ctile0 + cg * 8);
        float4 cnb = *(const float4*)(cn2 + ctile0 + cg * 8 + 4);
        float acc[8][8];
#pragma unroll
        for (int j = 0; j < 8; ++j) {
            acc[j][0] = -cna.x; acc[j][1] = -cna.y;
            acc[j][2] = -cna.z; acc[j][3] = -cna.w;
            acc[j][4] = -cnb.x; acc[j][5] = -cnb.y;
            acc[j][6] = -cnb.z; acc[j][7] = -cnb.w;
        }

        // ---- FMA over d: 4 ds_read_b128 per d for 64 FMA ----
        for (int dc = 0; dc < 16; ++dc) {
            const int cc0 = ((2 * cg + dc) & 31) * 4;
            const int cc1 = ((2 * cg + 1 + dc) & 31) * 4;
#pragma unroll
            for (int j4 = 0; j4 < 4; ++j4) {
                const int d = dc * 4 + j4;
                float4 xa = *(const float4*)&x_lds[d][xc0];
                float4 xb = *(const float4*)&x_lds[d][xc1];
                float4 ca = *(const float4*)&c_lds[d][cc0];
                float4 cb4 = *(const float4*)&c_lds[d][cc1];
                float xr[8] = {xa.x, xa.y, xa.z, xa.w, xb.x, xb.y, xb.z, xb.w};
                float cr[8] = {ca.x, ca.y, ca.z, ca.w, cb4.x, cb4.y, cb4.z, cb4.w};
#pragma unroll
                for (int j = 0; j < 8; ++j)
#pragma unroll
                    for (int m = 0; m < 8; ++m)
                        acc[j][m] = fmaf(xr[j], cr[m], acc[j][m]);
            }
        }

        // ---- fold into running best (ascending code + strict > = argmin-first) ----
#pragma unroll
        for (int j = 0; j < 8; ++j) {
#pragma unroll
            for (int m = 0; m < 8; ++m) {
                int code = ctile0 + cg * 8 + m;
                if (acc[j][m] > best_val[j]) { best_val[j] = acc[j][m]; best_idx[j] = code; }
            }
        }
    }

    // ---- cross-thread reduce per row (reuse LDS after barrier) ----
    __syncthreads();
    float* red_val = &c_lds[0][0];       // [128][17]
    int*   red_idx = (int*)&x_lds[0][0]; // [128][17]
#pragma unroll
    for (int j = 0; j < 8; ++j) {
        int rl = rg * 8 + j;
        red_val[rl * 17 + cg] = best_val[j];
        red_idx[rl * 17 + cg] = best_idx[j];
    }
    __syncthreads();
    if (t < RPB) {
        float bv = red_val[t * 17 + 0];
        int   bi = red_idx[t * 17 + 0];
#pragma unroll
        for (int c = 1; c < 16; ++c) {
            float v = red_val[t * 17 + c];
            int  id = red_idx[t * 17 + c];
            if (v > bv || (v == bv && id < bi)) { bv = v; bi = id; }
        }
        cand_val[(size_t)(row0 + t) * NQ + q] = bv;
        cand_idx[(size_t)(row0 + t) * NQ + q] = bi;
    }
}

// ---------------- kernel 2: combine quarters, write 1.0 + quantized ----------------
__global__ __launch_bounds__(256) void k_finish(const float* __restrict__ cb,
                                                const float* __restrict__ cand_val,
                                                const int* __restrict__ cand_idx,
                                                float* __restrict__ discrete,
                                                float* __restrict__ quantized) {
    __shared__ int sidx[256];
    const int t = threadIdx.x;
    const int row0 = blockIdx.x * 256;
    const int row = row0 + t;
    float bv = cand_val[(size_t)row * NQ + 0];
    int   bi = cand_idx[(size_t)row * NQ + 0];
#pragma unroll
    for (int q = 1; q < NQ; ++q) {
        float v = cand_val[(size_t)row * NQ + q];
        int  id = cand_idx[(size_t)row * NQ + q];
        if (v > bv || (v == bv && id < bi)) { bv = v; bi = id; }
    }
    sidx[t] = bi;
    discrete[(size_t)row * KCODES + bi] = 1.0f;
    __syncthreads();
#pragma unroll
    for (int i = 0; i < 16; ++i) {
        int e = i * 256 + t;
        int r = e >> 4, c = e & 15;
        float4 v = *((const float4*)(cb + (size_t)sidx[r] * DDIM) + c);
        *((float4*)(quantized + (size_t)(row0 + r) * DDIM) + c) = v;
    }
}

extern "C" void kernel_launch(void* const* d_in, const int* in_sizes, int n_in,
                              void* d_out, int out_size, void* d_ws, size_t ws_size,
                              hipStream_t stream) {
    const float* x  = (const float*)d_in[0];   // 16*32*32*64
    const float* cb = (const float*)d_in[1];   // 8192*64

    float* discrete  = (float*)d_out;                          // 16384*8192
    float* quantized = (float*)d_out + (size_t)NROWS * KCODES; // 16384*64

    float* cn2      = (float*)d_ws;                 // 8192 floats
    float* cand_val = cn2 + KCODES;                 // 16384*4 floats
    int*   cand_idx = (int*)(cand_val + NROWS * NQ);

    k_cn2<<<KCODES / 256, 256, 0, stream>>>(cb, cn2);
    k_main<<<(NROWS / RPB) * NQ, 256, 0, stream>>>(x, cb, cn2, discrete, cand_val, cand_idx);
    k_finish<<<NROWS / 256, 256, 0, stream>>>(cb, cand_val, cand_idx, discrete, quantized);
}

// Round 4
// 552.438 us; speedup vs baseline: 1.3142x; 1.2081x over previous
//
#include <hip/hip_runtime.h>

// VectorQuantizer: x[16384][64] fp32, codebook[8192][64] fp32
// out = concat(discrete one-hot [16384][8192] fp32, quantized [16384][64] fp32)
// argmin_k ||x-c_k||^2 == argmax_k (x.c_k - 0.5||c_k||^2)
//
// Strategy: exact fp32 dot products via fp16 hi/lo split + 8x mfma_f32_16x16x32_f16
// per 16-code tile (all 4 cross terms -> fp32-accurate, split is exact).
// Codebook pre-packed into MFMA B-fragment layout (2 MB, L2-resident) so the
// hot loop is pure global_load_dwordx4 + MFMA + compare; no LDS at all.

#define NROWS 16384
#define KCODES 8192
#define DDIM 64
#define NQ 4                 // code quarters (one per wave in a block)
#define QCODES (KCODES / NQ) // 2048
#define TILES_PER_Q (QCODES / 16) // 128

typedef float   f32x4 __attribute__((ext_vector_type(4)));
typedef _Float16 f16x8 __attribute__((ext_vector_type(8)));

// ---------------- kernel 0: cn2[k] = 0.5*||c_k||^2 (exact fp32) ----------------
__global__ __launch_bounds__(256) void k_cn2(const float* __restrict__ cb,
                                             float* __restrict__ cn2) {
    int i = blockIdx.x * 256 + threadIdx.x;
    const float4* c4 = (const float4*)(cb + (size_t)i * DDIM);
    float s = 0.f;
#pragma unroll
    for (int j = 0; j < 16; ++j) {
        float4 v = c4[j];
        s = fmaf(v.x, v.x, s); s = fmaf(v.y, v.y, s);
        s = fmaf(v.z, v.z, s); s = fmaf(v.w, v.w, s);
    }
    cn2[i] = 0.5f * s;
}

// ---------------- kernel 1: pack codebook into B-fragment layout ----------------
// packed[tile][frag][lane] : tile = code/16 (512), frag 0=hi k0..31, 1=hi k32..63,
// 2=lo k0..31, 3=lo k32..63; lane holds code=tile*16+(L&15), k=(L>>4)*8 + j.
// One thread per (tile, lane).
__global__ __launch_bounds__(256) void k_pack(const float* __restrict__ cb,
                                              f16x8* __restrict__ packed) {
    int tid = blockIdx.x * 256 + threadIdx.x;   // 0..32767
    int Tg = tid >> 6, L = tid & 63;
    int code = Tg * 16 + (L & 15);
    int koff = (L >> 4) * 8;
    const float* p = cb + (size_t)code * DDIM + koff;
    f16x8 h0, l0, h1, l1;
#pragma unroll
    for (int j = 0; j < 8; ++j) {
        float v = p[j];
        _Float16 h = (_Float16)v;
        h0[j] = h; l0[j] = (_Float16)(v - (float)h);
        float w = p[32 + j];
        _Float16 h2 = (_Float16)w;
        h1[j] = h2; l1[j] = (_Float16)(w - (float)h2);
    }
    f16x8* out = packed + (size_t)Tg * 256 + L;
    out[0]   = h0;
    out[64]  = h1;
    out[128] = l0;
    out[192] = l1;
}

// ---------------- kernel 2: main MFMA + argmax + zero-fill ----------------
// grid = 1024 blocks; block = 16 rows x 8192 codes; wave q = code quarter.
// Per wave: A-frags (4x f16x8) held in regs; 128 tiles of 16 codes:
//   4 coalesced dwordx4 B-frag loads + 8 MFMA + compare + 1 zero store.
__global__ __launch_bounds__(256) void k_main(const float* __restrict__ x,
                                              const f16x8* __restrict__ packed,
                                              const float* __restrict__ cn2,
                                              float* __restrict__ discrete,
                                              float* __restrict__ cand_val,
                                              int* __restrict__ cand_idx) {
    const int t = threadIdx.x;
    const int L = t & 63;        // lane
    const int q = t >> 6;        // wave = code quarter
    const int row0 = blockIdx.x * 16;
    const int lane15 = L & 15;
    const int quad = L >> 4;

    // ---- A fragments: rows row0..row0+15, exact fp16 hi/lo split ----
    const float* xp = x + (size_t)(row0 + lane15) * DDIM + quad * 8;
    f16x8 xh0, xl0, xh1, xl1;
#pragma unroll
    for (int j = 0; j < 8; ++j) {
        float v = xp[j];
        _Float16 h = (_Float16)v;
        xh0[j] = h; xl0[j] = (_Float16)(v - (float)h);
        float w = xp[32 + j];
        _Float16 h2 = (_Float16)w;
        xh1[j] = h2; xl1[j] = (_Float16)(w - (float)h2);
    }

    float bvv[4];
    int   bii[4];
#pragma unroll
    for (int r = 0; r < 4; ++r) { bvv[r] = -3.4e38f; bii[r] = 0; }

    const f32x4 zero4 = {0.f, 0.f, 0.f, 0.f};

    for (int i = 0; i < TILES_PER_Q; ++i) {
        const int ct = q * QCODES + i * 16;          // tile base code
        const f16x8* pb = packed + (size_t)(ct >> 4) * 256 + L;
        f16x8 ch0 = pb[0];
        f16x8 ch1 = pb[64];
        f16x8 cl0 = pb[128];
        f16x8 cl1 = pb[192];
        float cn = cn2[ct + lane15];

        // zero-fill one float4 per thread per tile (covers 16 rows x 8192 exactly)
        {
            int f = i * 256 + t;                      // 0..32767
            f32x4* dst = (f32x4*)(discrete + (size_t)(row0 + (f >> 11)) * KCODES) + (f & 2047);
            __builtin_nontemporal_store(zero4, dst);
        }

        f32x4 acc = {-cn, -cn, -cn, -cn};
        acc = __builtin_amdgcn_mfma_f32_16x16x32_f16(xh0, ch0, acc, 0, 0, 0);
        acc = __builtin_amdgcn_mfma_f32_16x16x32_f16(xh1, ch1, acc, 0, 0, 0);
        acc = __builtin_amdgcn_mfma_f32_16x16x32_f16(xl0, ch0, acc, 0, 0, 0);
        acc = __builtin_amdgcn_mfma_f32_16x16x32_f16(xl1, ch1, acc, 0, 0, 0);
        acc = __builtin_amdgcn_mfma_f32_16x16x32_f16(xh0, cl0, acc, 0, 0, 0);
        acc = __builtin_amdgcn_mfma_f32_16x16x32_f16(xh1, cl1, acc, 0, 0, 0);
        acc = __builtin_amdgcn_mfma_f32_16x16x32_f16(xl0, cl0, acc, 0, 0, 0);
        acc = __builtin_amdgcn_mfma_f32_16x16x32_f16(xl1, cl1, acc, 0, 0, 0);

        const int vcode = ct + lane15;               // this lane's code (col = L&15)
#pragma unroll
        for (int r = 0; r < 4; ++r)
            if (acc[r] > bvv[r]) { bvv[r] = acc[r]; bii[r] = vcode; }
    }

    // ---- reduce across the 16 lanes of each quad (same rows, different codes) ----
#pragma unroll
    for (int r = 0; r < 4; ++r) {
        float v = bvv[r];
        int  id = bii[r];
#pragma unroll
        for (int m = 1; m < 16; m <<= 1) {
            float ov = __shfl_xor(v, m, 64);
            int   oi = __shfl_xor(id, m, 64);
            if (ov > v || (ov == v && oi < id)) { v = ov; id = oi; }
        }
        if (lane15 == 0) {
            int row = row0 + quad * 4 + r;           // D row = quad*4 + reg
            cand_val[(size_t)row * NQ + q] = v;
            cand_idx[(size_t)row * NQ + q] = id;
        }
    }
}

// ---------------- kernel 3: combine quarters, write 1.0 + quantized ----------------
__global__ __launch_bounds__(256) void k_finish(const float* __restrict__ cb,
                                                const float* __restrict__ cand_val,
                                                const int* __restrict__ cand_idx,
                                                float* __restrict__ discrete,
                                                float* __restrict__ quantized) {
    __shared__ int sidx[256];
    const int t = threadIdx.x;
    const int row0 = blockIdx.x * 256;
    const int row = row0 + t;
    float bv = cand_val[(size_t)row * NQ + 0];
    int   bi = cand_idx[(size_t)row * NQ + 0];
#pragma unroll
    for (int q = 1; q < NQ; ++q) {
        float v = cand_val[(size_t)row * NQ + q];
        int  id = cand_idx[(size_t)row * NQ + q];
        if (v > bv || (v == bv && id < bi)) { bv = v; bi = id; }
    }
    sidx[t] = bi;
    discrete[(size_t)row * KCODES + bi] = 1.0f;
    __syncthreads();
#pragma unroll
    for (int i = 0; i < 16; ++i) {
        int e = i * 256 + t;
        int r = e >> 4, c = e & 15;
        float4 v = *((const float4*)(cb + (size_t)sidx[r] * DDIM) + c);
        *((float4*)(quantized + (size_t)(row0 + r) * DDIM) + c) = v;
    }
}

extern "C" void kernel_launch(void* const* d_in, const int* in_sizes, int n_in,
                              void* d_out, int out_size, void* d_ws, size_t ws_size,
                              hipStream_t stream) {
    const float* x  = (const float*)d_in[0];   // 16*32*32*64
    const float* cb = (const float*)d_in[1];   // 8192*64

    float* discrete  = (float*)d_out;                          // 16384*8192
    float* quantized = (float*)d_out + (size_t)NROWS * KCODES; // 16384*64

    // packed B-fragments (2 MB) live in the quantized output region (4 MB):
    // k_main only reads it; k_finish overwrites quantized afterwards.
    f16x8* packed = (f16x8*)quantized;

    float* cn2      = (float*)d_ws;                 // 8192 floats
    float* cand_val = cn2 + KCODES;                 // 16384*4 floats
    int*   cand_idx = (int*)(cand_val + NROWS * NQ);

    k_cn2<<<KCODES / 256, 256, 0, stream>>>(cb, cn2);
    k_pack<<<(KCODES / 16) * 64 / 256, 256, 0, stream>>>(cb, packed);
    k_main<<<NROWS / 16, 256, 0, stream>>>(x, packed, cn2, discrete, cand_val, cand_idx);
    k_finish<<<NROWS / 256, 256, 0, stream>>>(cb, cand_val, cand_idx, discrete, quantized);
}